// Round 5
// baseline (319.576 us; speedup 1.0000x reference)
//
#include <hip/hip_runtime.h>

// ZBL pair potential + segment-sum into NUM_SYSTEMS bins.
// Inputs (setup_inputs order):
//  0: local_d_ij               float32 [16M]
//  1: radii_table              float32 [97]
//  2: local_pair_indices       int32   [2, 16M]  (row 0 = idx_i, row 1 = idx_j)
//  3: atomic_numbers           int32   [1M]
//  4: atomic_subsystem_indices int32   [1M]
// Output: float32 [10000] per-system energy.
//
// R2: LDS histograms + tree reduction (global atomics were the R1 serializer).
// R4: 8 edges/thread, up-front gathers (MLP) — NEUTRAL vs R3 => per-thread
//     MLP is not the limit.
// R5: fully branchless inner loop. Exec-masked branch bodies issue anyway
//     (random masks are never whole-wave-false), so branches only added mask
//     churn + waitcnt fragmentation. Compute all edges; kill dead lanes with
//     cndmask; unconditional LDS atomic with dead lanes routed to per-lane
//     dummy pad bins (distinct banks; avoids same-address serialization).

constexpr int MAXZ = 97;
constexpr int NBINS_PAD = 10240;   // 10000 real bins + pad; pad holds dummies
constexpr int DUMMY_BASE = NBINS_PAD - 64;  // 10176..10239: per-lane trash bins
constexpr int NREP = 512;          // histogram replicas = grid of main kernel
constexpr int NPART = 32;          // first-stage reduction fan-in groups

constexpr double LOG2E_D = 1.4426950408889634;
constexpr float A_INV = (float)(1.0 / (0.8854 * 0.0529177210903));
constexpr float C1 = (float)(-3.2    * LOG2E_D);
constexpr float C2 = (float)(-0.9423 * LOG2E_D);
constexpr float C3 = (float)(-0.4029 * LOG2E_D);
constexpr float C4 = (float)(-0.2016 * LOG2E_D);
constexpr float COUL = 138.9354576f;

typedef int   iv4 __attribute__((ext_vector_type(4)));
typedef float fv4 __attribute__((ext_vector_type(4)));
typedef float fv2 __attribute__((ext_vector_type(2)));

__global__ void zero_kernel(float* __restrict__ out, int n) {
    int i = blockIdx.x * blockDim.x + threadIdx.x;
    if (i < n) out[i] = 0.0f;
}

// packed[i] = z | (seg << 8)   (z < 97 fits in 8 bits, seg < 10000 fits in 24)
__global__ void pack_kernel(const int* __restrict__ z,
                            const int* __restrict__ seg,
                            unsigned int* __restrict__ packed, int n) {
    int i = blockIdx.x * blockDim.x + threadIdx.x;
    if (i < n)
        packed[i] = (unsigned int)z[i] | ((unsigned int)seg[i] << 8);
}

// ---------------- main path: LDS histogram, no global atomics ---------------

__global__ __launch_bounds__(1024)
void zbl_hist_kernel(const float* __restrict__ d_ij,
                     const float* __restrict__ radii,
                     const int* __restrict__ idx_i,
                     const int* __restrict__ idx_j,
                     const unsigned int* __restrict__ packed,
                     float* __restrict__ rep,     // [NREP][NBINS_PAD]
                     int n_edges) {
    __shared__ float s_hist[NBINS_PAD];  // 40 KiB
    __shared__ fv2 s_rz[128];            // {radius, z^0.23} fused -> ds_read_b64
    const int t = threadIdx.x;
    const int lane = t & 63;

    for (int b = t; b < NBINS_PAD; b += 1024) s_hist[b] = 0.0f;
    if (t < 128) {
        fv2 v;
        v.x = (t < MAXZ) ? radii[t] : 0.0f;
        v.y = __builtin_exp2f(0.23f * __builtin_log2f((float)t));  // z^0.23
        s_rz[t] = v;
    }
    __syncthreads();

    const int ngrp = n_edges >> 3;   // groups of 8 edges
    const int stride = gridDim.x * blockDim.x;
    for (int g = blockIdx.x * blockDim.x + t; g < ngrp; g += stride) {
        const iv4* pii = reinterpret_cast<const iv4*>(idx_i) + 2 * g;
        const iv4* pjj = reinterpret_cast<const iv4*>(idx_j) + 2 * g;
        const fv4* pdd = reinterpret_cast<const fv4*>(d_ij) + 2 * g;
        // Non-temporal stream loads: don't evict the 4MB gather table from L2.
        iv4 ii0 = __builtin_nontemporal_load(pii);
        iv4 ii1 = __builtin_nontemporal_load(pii + 1);
        iv4 jj0 = __builtin_nontemporal_load(pjj);
        iv4 jj1 = __builtin_nontemporal_load(pjj + 1);
        fv4 dd0 = __builtin_nontemporal_load(pdd);
        fv4 dd1 = __builtin_nontemporal_load(pdd + 1);

        int ia[8], ja[8];
        float da[8];
#pragma unroll
        for (int k = 0; k < 4; ++k) {
            ia[k] = ii0[k]; ia[4 + k] = ii1[k];
            ja[k] = jj0[k]; ja[4 + k] = jj1[k];
            da[k] = dd0[k]; da[4 + k] = dd1[k];
        }

        // All 16 gathers issued back-to-back, no control flow. Dead lanes
        // (i>=j) read packed[0] — a single always-hot line.
        unsigned int pia[8], pja[8];
#pragma unroll
        for (int k = 0; k < 8; ++k) {
            bool m = ia[k] < ja[k];
            pia[k] = packed[m ? ia[k] : 0];
            pja[k] = packed[m ? ja[k] : 0];
        }

        // Branchless compute + unconditional LDS atomic.
#pragma unroll
        for (int k = 0; k < 8; ++k) {
            bool m = ia[k] < ja[k];
            int zi = (int)(pia[k] & 0xFFu);
            int zj = (int)(pja[k] & 0xFFu);
            int seg = (int)(pia[k] >> 8);
            fv2 rzi = s_rz[zi];
            fv2 rzj = s_rz[zj];
            float d = da[k];
            float rsum = rzi.x + rzj.x;
            bool ok = m && (d < rsum);
            float dA = d * (rzi.y + rzj.y) * A_INV;
            float f = 0.1818f  * __builtin_exp2f(C1 * dA)
                    + 0.5099f  * __builtin_exp2f(C2 * dA)
                    + 0.2802f  * __builtin_exp2f(C3 * dA)
                    + 0.02817f * __builtin_exp2f(C4 * dA);
            float tt = d * __builtin_amdgcn_rcpf(rsum);          // in [0,1)
            // cos(pi*t) = v_cos(t/2)  (v_cos input is in revolutions)
            float phi = 0.5f * (__builtin_amdgcn_cosf(0.5f * tt) + 1.0f);
            float e = f * phi * (COUL * (float)zi * (float)zj)
                    * __builtin_amdgcn_rcpf(d);
            e = ok ? e : 0.0f;
            // Dead-gather lanes all share seg(atom0): route them to per-lane
            // dummy pad bins (distinct banks) to avoid same-address LDS
            // atomic serialization. Valid-but-zero lanes hit real (random)
            // bins with e=0 — harmless.
            int segk = m ? seg : (DUMMY_BASE + lane);
            atomicAdd(&s_hist[segk], e);
        }
    }

    // Tail (n_edges % 8 != 0): at most 7 edges, one thread handles them.
    if (blockIdx.x == 0 && t == 0) {
        for (int e = ngrp << 3; e < n_edges; ++e) {
            int i = idx_i[e], j = idx_j[e];
            if (i < j) {
                unsigned int pi = packed[i], pj = packed[j];
                int zi = (int)(pi & 0xFFu), zj = (int)(pj & 0xFFu);
                fv2 rzi = s_rz[zi], rzj = s_rz[zj];
                float d = d_ij[e];
                float rsum = rzi.x + rzj.x;
                if (d < rsum) {
                    float dA = d * (rzi.y + rzj.y) * A_INV;
                    float f = 0.1818f  * __builtin_exp2f(C1 * dA)
                            + 0.5099f  * __builtin_exp2f(C2 * dA)
                            + 0.2802f  * __builtin_exp2f(C3 * dA)
                            + 0.02817f * __builtin_exp2f(C4 * dA);
                    float tt = d * __builtin_amdgcn_rcpf(rsum);
                    float phi = 0.5f * (__builtin_amdgcn_cosf(0.5f * tt) + 1.0f);
                    float en = f * phi * (COUL * (float)zi * (float)zj)
                             * __builtin_amdgcn_rcpf(d);
                    atomicAdd(&s_hist[(int)(pi >> 8)], en);
                }
            }
        }
    }

    __syncthreads();
    // Flush histogram to this block's replica row (coalesced float4 stores).
    fv4* __restrict__ rp =
        reinterpret_cast<fv4*>(rep + (size_t)blockIdx.x * NBINS_PAD);
    const fv4* sh = reinterpret_cast<const fv4*>(s_hist);
    for (int q = t; q < NBINS_PAD / 4; q += 1024)
        rp[q] = sh[q];
}

// Stage 1: partial[s][bin] = sum over replica rows r = s, s+NPART, ...
__global__ __launch_bounds__(256)
void reduce1_kernel(const float* __restrict__ rep,
                    float* __restrict__ partial) {
    int bin = blockIdx.x * 256 + threadIdx.x;
    int s = blockIdx.y;
    float acc = 0.0f;
    for (int r = s; r < NREP; r += NPART)
        acc += rep[(size_t)r * NBINS_PAD + bin];
    partial[(size_t)s * NBINS_PAD + bin] = acc;
}

// Stage 2: out[bin] = sum over NPART partials. Only real bins (<out_size) are
// written — dummy pad bins never reach the output.
__global__ __launch_bounds__(256)
void reduce2_kernel(const float* __restrict__ partial,
                    float* __restrict__ out, int out_size) {
    int bin = blockIdx.x * 256 + threadIdx.x;
    if (bin < out_size) {
        float acc = 0.0f;
        for (int s = 0; s < NPART; ++s)
            acc += partial[(size_t)s * NBINS_PAD + bin];
        out[bin] = acc;
    }
}

// ---------------- fallback path (R1): direct global atomics ----------------

template <bool PACKED>
__global__ __launch_bounds__(256)
void zbl_atomic_kernel(const float* __restrict__ d_ij,
                       const float* __restrict__ radii,
                       const int* __restrict__ idx_i,
                       const int* __restrict__ idx_j,
                       const unsigned int* __restrict__ packed,
                       const int* __restrict__ atomz,
                       const int* __restrict__ subsys,
                       float* __restrict__ out,
                       int nchunk) {
    __shared__ fv2 s_rz[128];
    int t = threadIdx.x;
    if (t < 128) {
        fv2 v;
        v.x = (t < MAXZ) ? radii[t] : 0.0f;
        v.y = __builtin_exp2f(0.23f * __builtin_log2f((float)t));
        s_rz[t] = v;
    }
    __syncthreads();

    int chunk = blockIdx.x * blockDim.x + threadIdx.x;
    if (chunk >= nchunk) return;

    iv4 ii = reinterpret_cast<const iv4*>(idx_i)[chunk];
    iv4 jj = reinterpret_cast<const iv4*>(idx_j)[chunk];
    fv4 dd = reinterpret_cast<const fv4*>(d_ij)[chunk];

#pragma unroll
    for (int k = 0; k < 4; ++k) {
        int i = ii[k];
        int j = jj[k];
        float d = dd[k];
        if (i < j) {
            int zi, zj, seg;
            if (PACKED) {
                unsigned int pi = packed[i];
                unsigned int pj = packed[j];
                zi = (int)(pi & 0xFFu);
                zj = (int)(pj & 0xFFu);
                seg = (int)(pi >> 8);
            } else {
                zi = atomz[i];
                zj = atomz[j];
                seg = subsys[i];
            }
            fv2 rzi = s_rz[zi], rzj = s_rz[zj];
            float rsum = rzi.x + rzj.x;
            if (d < rsum) {
                float dA = d * (rzi.y + rzj.y) * A_INV;
                float f = 0.1818f  * __builtin_exp2f(C1 * dA)
                        + 0.5099f  * __builtin_exp2f(C2 * dA)
                        + 0.2802f  * __builtin_exp2f(C3 * dA)
                        + 0.02817f * __builtin_exp2f(C4 * dA);
                float tt = d * __builtin_amdgcn_rcpf(rsum);
                float phi = 0.5f * (__builtin_amdgcn_cosf(0.5f * tt) + 1.0f);
                float e = f * phi * (COUL * (float)zi * (float)zj)
                        * __builtin_amdgcn_rcpf(d);
                atomicAdd(out + seg, e);
            }
        }
    }
}

extern "C" void kernel_launch(void* const* d_in, const int* in_sizes, int n_in,
                              void* d_out, int out_size, void* d_ws, size_t ws_size,
                              hipStream_t stream) {
    const float* d_ij  = (const float*)d_in[0];
    const float* radii = (const float*)d_in[1];
    const int* pairs   = (const int*)d_in[2];
    const int* atomz   = (const int*)d_in[3];
    const int* subsys  = (const int*)d_in[4];
    float* out = (float*)d_out;

    const int n_edges = in_sizes[2] / 2;   // 16,000,000
    const int n_atoms = in_sizes[3];       // 1,000,000
    const int* idx_i = pairs;
    const int* idx_j = pairs + n_edges;

    const size_t packed_bytes = (size_t)n_atoms * sizeof(unsigned int);
    const size_t rep_bytes = (size_t)NREP * NBINS_PAD * sizeof(float);
    const size_t part_bytes = (size_t)NPART * NBINS_PAD * sizeof(float);

    if (ws_size >= packed_bytes + rep_bytes + part_bytes) {
        unsigned int* packed = (unsigned int*)d_ws;
        float* rep = (float*)((char*)d_ws + packed_bytes);
        float* partial = (float*)((char*)d_ws + packed_bytes + rep_bytes);

        pack_kernel<<<(n_atoms + 255) / 256, 256, 0, stream>>>(atomz, subsys,
                                                               packed, n_atoms);
        zbl_hist_kernel<<<NREP, 1024, 0, stream>>>(
            d_ij, radii, idx_i, idx_j, packed, rep, n_edges);
        dim3 g1(NBINS_PAD / 256, NPART);
        reduce1_kernel<<<g1, 256, 0, stream>>>(rep, partial);
        reduce2_kernel<<<(out_size + 255) / 256, 256, 0, stream>>>(
            partial, out, out_size);
    } else {
        // Fallback: direct-atomic path (R1)
        zero_kernel<<<(out_size + 255) / 256, 256, 0, stream>>>(out, out_size);
        const int nchunk = n_edges / 4;
        const int blocks = (nchunk + 255) / 256;
        if (ws_size >= packed_bytes) {
            unsigned int* packed = (unsigned int*)d_ws;
            pack_kernel<<<(n_atoms + 255) / 256, 256, 0, stream>>>(
                atomz, subsys, packed, n_atoms);
            zbl_atomic_kernel<true><<<blocks, 256, 0, stream>>>(
                d_ij, radii, idx_i, idx_j, packed, atomz, subsys, out, nchunk);
        } else {
            zbl_atomic_kernel<false><<<blocks, 256, 0, stream>>>(
                d_ij, radii, idx_i, idx_j, nullptr, atomz, subsys, out, nchunk);
        }
    }
}

// Round 6
// 318.424 us; speedup vs baseline: 1.0036x; 1.0036x over previous
//
#include <hip/hip_runtime.h>

// ZBL pair potential + segment-sum into NUM_SYSTEMS bins.
// Inputs (setup_inputs order):
//  0: local_d_ij               float32 [16M]
//  1: radii_table              float32 [97]
//  2: local_pair_indices       int32   [2, 16M]  (row 0 = idx_i, row 1 = idx_j)
//  3: atomic_numbers           int32   [1M]
//  4: atomic_subsystem_indices int32   [1M]
// Output: float32 [10000] per-system energy.
//
// R2: LDS histograms + tree reduction (global atomics were the R1 serializer).
// R4/R5: MLP + branchless — NEUTRAL. Duration invariant across gather-lane
//   count, atomic count, and VALU count => bound by issued instructions/edge
//   (2 divergent gathers + 1 math body, mask-independent).
// R6: wave-level stream compaction. Pack passing (i<j) edges into a per-wave
//   LDS circular queue (ballot+mbcnt rank); run gathers+math only in fully
//   dense 64-lane rounds. Halves gather instrs, math, and LDS atomics/edge.

constexpr int MAXZ = 97;
constexpr int NBINS_PAD = 10016;   // 10000 bins padded to /4 (fits LDS budget)
constexpr int NREP = 512;          // histogram replicas = grid of main kernel
constexpr int NPART = 32;          // first-stage reduction fan-in groups
constexpr int WAVES_PER_BLOCK = 16;
constexpr int QCAP = 128;          // per-wave queue slots (power of 2)

constexpr double LOG2E_D = 1.4426950408889634;
constexpr float A_INV = (float)(1.0 / (0.8854 * 0.0529177210903));
constexpr float C1 = (float)(-3.2    * LOG2E_D);
constexpr float C2 = (float)(-0.9423 * LOG2E_D);
constexpr float C3 = (float)(-0.4029 * LOG2E_D);
constexpr float C4 = (float)(-0.2016 * LOG2E_D);
constexpr float COUL = 138.9354576f;

typedef int   iv4 __attribute__((ext_vector_type(4)));
typedef float fv4 __attribute__((ext_vector_type(4)));
typedef float fv2 __attribute__((ext_vector_type(2)));

__global__ void zero_kernel(float* __restrict__ out, int n) {
    int i = blockIdx.x * blockDim.x + threadIdx.x;
    if (i < n) out[i] = 0.0f;
}

// packed[i] = z | (seg << 8)   (z < 97 fits in 8 bits, seg < 10000 fits in 24)
__global__ void pack_kernel(const int* __restrict__ z,
                            const int* __restrict__ seg,
                            unsigned int* __restrict__ packed, int n) {
    int i = blockIdx.x * blockDim.x + threadIdx.x;
    if (i < n)
        packed[i] = (unsigned int)z[i] | ((unsigned int)seg[i] << 8);
}

// Dense edge processing: gathers + math + LDS-hist atomic. All lanes valid.
__device__ __forceinline__ void process_edge(int i, int j, float d,
                                             const unsigned int* __restrict__ packed,
                                             const fv2* s_rz,
                                             float* s_hist) {
    unsigned int pi = packed[i];
    unsigned int pj = packed[j];
    int zi = (int)(pi & 0xFFu);
    int zj = (int)(pj & 0xFFu);
    int seg = (int)(pi >> 8);
    fv2 rzi = s_rz[zi];
    fv2 rzj = s_rz[zj];
    float rsum = rzi.x + rzj.x;
    bool ok = d < rsum;
    float dA = d * (rzi.y + rzj.y) * A_INV;
    float f = 0.1818f  * __builtin_exp2f(C1 * dA)
            + 0.5099f  * __builtin_exp2f(C2 * dA)
            + 0.2802f  * __builtin_exp2f(C3 * dA)
            + 0.02817f * __builtin_exp2f(C4 * dA);
    float tt = d * __builtin_amdgcn_rcpf(rsum);          // in [0,1)
    // cos(pi*t) = v_cos(t/2)  (v_cos input is in revolutions)
    float phi = 0.5f * (__builtin_amdgcn_cosf(0.5f * tt) + 1.0f);
    float e = f * phi * (COUL * (float)zi * (float)zj)
            * __builtin_amdgcn_rcpf(d);
    e = ok ? e : 0.0f;
    atomicAdd(&s_hist[seg], e);   // seg is real (valid edge) — random bin
}

// ---------------- main path: compaction + LDS histogram ---------------------

__global__ __launch_bounds__(1024)
void zbl_hist_kernel(const float* __restrict__ d_ij,
                     const float* __restrict__ radii,
                     const int* __restrict__ idx_i,
                     const int* __restrict__ idx_j,
                     const unsigned int* __restrict__ packed,
                     float* __restrict__ rep,     // [NREP][NBINS_PAD]
                     int n_edges) {
    __shared__ float s_hist[NBINS_PAD];               // 40064 B
    __shared__ fv2   s_rz[100];                       //   800 B {radius, z^0.23}
    __shared__ int   s_qi[WAVES_PER_BLOCK * QCAP];    //  8192 B
    __shared__ int   s_qj[WAVES_PER_BLOCK * QCAP];    //  8192 B
    __shared__ float s_qd[WAVES_PER_BLOCK * QCAP];    //  8192 B
    const int t = threadIdx.x;
    const int lane = t & 63;
    const int wave = t >> 6;
    const int qbase = wave * QCAP;

    for (int b = t; b < NBINS_PAD; b += 1024) s_hist[b] = 0.0f;
    if (t < 100) {
        fv2 v;
        v.x = (t < MAXZ) ? radii[t] : 0.0f;
        v.y = __builtin_exp2f(0.23f * __builtin_log2f((float)t));  // z^0.23
        s_rz[t] = v;
    }
    __syncthreads();

    const int nbatch = (n_edges + 63) >> 6;   // 64-edge batches
    const int wave_gid = (blockIdx.x << 4) + wave;
    const int wstride = gridDim.x << 4;       // total waves in grid

    int head = 0;   // next unprocessed slot (wave-uniform)
    int q = 0;      // queued edge count (wave-uniform)

    for (int b = wave_gid; b < nbatch; b += wstride) {
        int e = (b << 6) + lane;
        // Coalesced non-temporal stream loads (1 edge/lane).
        bool inb = e < n_edges;
        int eidx = inb ? e : 0;
        int i = __builtin_nontemporal_load(idx_i + eidx);
        int j = __builtin_nontemporal_load(idx_j + eidx);
        float d = __builtin_nontemporal_load(d_ij + eidx);
        bool m = inb && (i < j);

        unsigned long long bal = __ballot(m);
        int rank = __builtin_amdgcn_mbcnt_hi(
            (unsigned int)(bal >> 32),
            __builtin_amdgcn_mbcnt_lo((unsigned int)bal, 0));
        int c = __popcll(bal);

        if (m) {  // consecutive ranks -> consecutive slots -> conflict-free
            int slot = qbase + ((head + q + rank) & (QCAP - 1));
            s_qi[slot] = i;
            s_qj[slot] = j;
            s_qd[slot] = d;
        }
        q += c;

        if (q >= 64) {  // wave-uniform: one fully-dense process round
            int slot = qbase + ((head + lane) & (QCAP - 1));
            int qi = s_qi[slot];
            int qj = s_qj[slot];
            float qd = s_qd[slot];
            head = (head + 64) & (QCAP - 1);
            q -= 64;
            process_edge(qi, qj, qd, packed, s_rz, s_hist);
        }
    }

    // Drain remaining (<64) queued edges, exec-masked.
    if (lane < q) {
        int slot = qbase + ((head + lane) & (QCAP - 1));
        process_edge(s_qi[slot], s_qj[slot], s_qd[slot], packed, s_rz, s_hist);
    }

    __syncthreads();
    // Flush histogram to this block's replica row (coalesced float4 stores).
    fv4* __restrict__ rp =
        reinterpret_cast<fv4*>(rep + (size_t)blockIdx.x * NBINS_PAD);
    const fv4* sh = reinterpret_cast<const fv4*>(s_hist);
    for (int qv = t; qv < NBINS_PAD / 4; qv += 1024)
        rp[qv] = sh[qv];
}

// Stage 1: partial[s][bin] = sum over replica rows r = s, s+NPART, ...
__global__ __launch_bounds__(256)
void reduce1_kernel(const float* __restrict__ rep,
                    float* __restrict__ partial) {
    int bin = blockIdx.x * 256 + threadIdx.x;
    if (bin < NBINS_PAD) {
        int s = blockIdx.y;
        float acc = 0.0f;
        for (int r = s; r < NREP; r += NPART)
            acc += rep[(size_t)r * NBINS_PAD + bin];
        partial[(size_t)s * NBINS_PAD + bin] = acc;
    }
}

// Stage 2: out[bin] = sum over NPART partials.
__global__ __launch_bounds__(256)
void reduce2_kernel(const float* __restrict__ partial,
                    float* __restrict__ out, int out_size) {
    int bin = blockIdx.x * 256 + threadIdx.x;
    if (bin < out_size) {
        float acc = 0.0f;
        for (int s = 0; s < NPART; ++s)
            acc += partial[(size_t)s * NBINS_PAD + bin];
        out[bin] = acc;
    }
}

// ---------------- fallback path (R1): direct global atomics ----------------

template <bool PACKED>
__global__ __launch_bounds__(256)
void zbl_atomic_kernel(const float* __restrict__ d_ij,
                       const float* __restrict__ radii,
                       const int* __restrict__ idx_i,
                       const int* __restrict__ idx_j,
                       const unsigned int* __restrict__ packed,
                       const int* __restrict__ atomz,
                       const int* __restrict__ subsys,
                       float* __restrict__ out,
                       int nchunk) {
    __shared__ fv2 s_rz[100];
    int t = threadIdx.x;
    if (t < 100) {
        fv2 v;
        v.x = (t < MAXZ) ? radii[t] : 0.0f;
        v.y = __builtin_exp2f(0.23f * __builtin_log2f((float)t));
        s_rz[t] = v;
    }
    __syncthreads();

    int chunk = blockIdx.x * blockDim.x + threadIdx.x;
    if (chunk >= nchunk) return;

    iv4 ii = reinterpret_cast<const iv4*>(idx_i)[chunk];
    iv4 jj = reinterpret_cast<const iv4*>(idx_j)[chunk];
    fv4 dd = reinterpret_cast<const fv4*>(d_ij)[chunk];

#pragma unroll
    for (int k = 0; k < 4; ++k) {
        int i = ii[k];
        int j = jj[k];
        float d = dd[k];
        if (i < j) {
            int zi, zj, seg;
            if (PACKED) {
                unsigned int pi = packed[i];
                unsigned int pj = packed[j];
                zi = (int)(pi & 0xFFu);
                zj = (int)(pj & 0xFFu);
                seg = (int)(pi >> 8);
            } else {
                zi = atomz[i];
                zj = atomz[j];
                seg = subsys[i];
            }
            fv2 rzi = s_rz[zi], rzj = s_rz[zj];
            float rsum = rzi.x + rzj.x;
            if (d < rsum) {
                float dA = d * (rzi.y + rzj.y) * A_INV;
                float f = 0.1818f  * __builtin_exp2f(C1 * dA)
                        + 0.5099f  * __builtin_exp2f(C2 * dA)
                        + 0.2802f  * __builtin_exp2f(C3 * dA)
                        + 0.02817f * __builtin_exp2f(C4 * dA);
                float tt = d * __builtin_amdgcn_rcpf(rsum);
                float phi = 0.5f * (__builtin_amdgcn_cosf(0.5f * tt) + 1.0f);
                float e = f * phi * (COUL * (float)zi * (float)zj)
                        * __builtin_amdgcn_rcpf(d);
                atomicAdd(out + seg, e);
            }
        }
    }
}

extern "C" void kernel_launch(void* const* d_in, const int* in_sizes, int n_in,
                              void* d_out, int out_size, void* d_ws, size_t ws_size,
                              hipStream_t stream) {
    const float* d_ij  = (const float*)d_in[0];
    const float* radii = (const float*)d_in[1];
    const int* pairs   = (const int*)d_in[2];
    const int* atomz   = (const int*)d_in[3];
    const int* subsys  = (const int*)d_in[4];
    float* out = (float*)d_out;

    const int n_edges = in_sizes[2] / 2;   // 16,000,000
    const int n_atoms = in_sizes[3];       // 1,000,000
    const int* idx_i = pairs;
    const int* idx_j = pairs + n_edges;

    const size_t packed_bytes = (size_t)n_atoms * sizeof(unsigned int);
    const size_t rep_bytes = (size_t)NREP * NBINS_PAD * sizeof(float);
    const size_t part_bytes = (size_t)NPART * NBINS_PAD * sizeof(float);

    if (ws_size >= packed_bytes + rep_bytes + part_bytes) {
        unsigned int* packed = (unsigned int*)d_ws;
        float* rep = (float*)((char*)d_ws + packed_bytes);
        float* partial = (float*)((char*)d_ws + packed_bytes + rep_bytes);

        pack_kernel<<<(n_atoms + 255) / 256, 256, 0, stream>>>(atomz, subsys,
                                                               packed, n_atoms);
        zbl_hist_kernel<<<NREP, 1024, 0, stream>>>(
            d_ij, radii, idx_i, idx_j, packed, rep, n_edges);
        dim3 g1((NBINS_PAD + 255) / 256, NPART);
        reduce1_kernel<<<g1, 256, 0, stream>>>(rep, partial);
        reduce2_kernel<<<(out_size + 255) / 256, 256, 0, stream>>>(
            partial, out, out_size);
    } else {
        // Fallback: direct-atomic path (R1)
        zero_kernel<<<(out_size + 255) / 256, 256, 0, stream>>>(out, out_size);
        const int nchunk = n_edges / 4;
        const int blocks = (nchunk + 255) / 256;
        if (ws_size >= packed_bytes) {
            unsigned int* packed = (unsigned int*)d_ws;
            pack_kernel<<<(n_atoms + 255) / 256, 256, 0, stream>>>(
                atomz, subsys, packed, n_atoms);
            zbl_atomic_kernel<true><<<blocks, 256, 0, stream>>>(
                d_ij, radii, idx_i, idx_j, packed, atomz, subsys, out, nchunk);
        } else {
            zbl_atomic_kernel<false><<<blocks, 256, 0, stream>>>(
                d_ij, radii, idx_i, idx_j, nullptr, atomz, subsys, out, nchunk);
        }
    }
}